// Round 5
// baseline (305.740 us; speedup 1.0000x reference)
//
#include <hip/hip_runtime.h>
#include <math.h>

#define B_SZ 8192
#define DIM 2048
#define NK 256

typedef _Float16 h8 __attribute__((ext_vector_type(8)));
typedef float f4 __attribute__((ext_vector_type(4)));
typedef unsigned short u16;
typedef u16 u16x8 __attribute__((ext_vector_type(8)));

// ================= circuit helpers (register statevector, 1 sim per wave) =================
// flat index j = r*64 + lane ; j bits [5:0]=lane, [10:6]=r. wire w lives at bit 10-w.

template <int R>
__device__ __forceinline__ void cnot_ring(float (&ar)[32], float (&ai)[32], int lane) {
    #pragma unroll
    for (int i = 0; i < 11; ++i) {
        const int c = i, tq = (i + R) % 11;
        const int pc = 10 - c, pt = 10 - tq;
        if (pt >= 6) {                      // target in register bits: in-lane swap
            const int rb = pt - 6;
            #pragma unroll
            for (int r0 = 0; r0 < 32; ++r0) {
                if ((r0 >> rb) & 1) continue;
                const int r1 = r0 | (1 << rb);
                if (pc >= 6) {
                    if ((r0 >> (pc - 6)) & 1) {
                        float t0 = ar[r0]; ar[r0] = ar[r1]; ar[r1] = t0;
                        float t1 = ai[r0]; ai[r0] = ai[r1]; ai[r1] = t1;
                    }
                } else {
                    bool ctl = ((lane >> pc) & 1) != 0;
                    float t0 = ar[r0]; ar[r0] = ctl ? ar[r1] : ar[r0]; ar[r1] = ctl ? t0 : ar[r1];
                    float t1 = ai[r0]; ai[r0] = ctl ? ai[r1] : ai[r0]; ai[r1] = ctl ? t1 : ai[r1];
                }
            }
        } else {                            // target in lane bits: shuffle + select
            const int lm = 1 << pt;
            #pragma unroll
            for (int r = 0; r < 32; ++r) {
                if (pc >= 6) {
                    if ((r >> (pc - 6)) & 1) {
                        ar[r] = __shfl_xor(ar[r], lm, 64);
                        ai[r] = __shfl_xor(ai[r], lm, 64);
                    }
                } else {
                    float pr = __shfl_xor(ar[r], lm, 64);
                    float pi = __shfl_xor(ai[r], lm, 64);
                    bool ctl = ((lane >> pc) & 1) != 0;
                    ar[r] = ctl ? pr : ar[r];
                    ai[r] = ctl ? pi : ai[r];
                }
            }
        }
    }
}

__device__ __forceinline__ void circuit_sim(int k, const float* __restrict__ dp,
                                            _Float16* __restrict__ Arb,
                                            _Float16* __restrict__ Aib, int lane) {
    float ar[32], ai[32];
    const int tgt = k << 3;
    const int tr = tgt >> 6, tl = tgt & 63;
    #pragma unroll
    for (int r = 0; r < 32; ++r) {
        ar[r] = (r == tr && lane == tl) ? 1.f : 0.f;
        ai[r] = 0.f;
    }
    for (int l = 0; l < 3; ++l) {
        const float* plp = dp + l * 33;
        #pragma unroll
        for (int w = 0; w < 11; ++w) {
            float phi = plp[w * 3 + 0], th = plp[w * 3 + 1], om = plp[w * 3 + 2];
            float cc = cosf(0.5f * th), ss = sinf(0.5f * th);
            float a = 0.5f * (phi + om), bb = 0.5f * (phi - om);
            float ca = cosf(a), sa = sinf(a), cb2 = cosf(bb), sb2 = sinf(bb);
            float m00r =  ca * cc, m00i = -sa * cc;
            float m01r = -cb2 * ss, m01i = -sb2 * ss;
            float m10r =  cb2 * ss, m10i = -sb2 * ss;
            float m11r =  ca * cc, m11i =  sa * cc;
            const int sh = 10 - w;
            if (sh >= 6) {                  // pair within lane, across registers
                const int rb = sh - 6;
                #pragma unroll
                for (int r0 = 0; r0 < 32; ++r0) {
                    if ((r0 >> rb) & 1) continue;
                    const int r1 = r0 | (1 << rb);
                    float a0r = ar[r0], a0i = ai[r0], a1r = ar[r1], a1i = ai[r1];
                    ar[r0] = m00r * a0r - m00i * a0i + m01r * a1r - m01i * a1i;
                    ai[r0] = m00r * a0i + m00i * a0r + m01r * a1i + m01i * a1r;
                    ar[r1] = m10r * a0r - m10i * a0i + m11r * a1r - m11i * a1i;
                    ai[r1] = m10r * a0i + m10i * a0r + m11r * a1i + m11i * a1r;
                }
            } else {                        // pair across lanes: shuffle
                const int lm = 1 << sh;
                const bool hi = (lane & lm) != 0;
                const float mAr = hi ? m10r : m00r, mAi = hi ? m10i : m00i;
                const float mBr = hi ? m11r : m01r, mBi = hi ? m11i : m01i;
                #pragma unroll
                for (int r = 0; r < 32; ++r) {
                    float pr = __shfl_xor(ar[r], lm, 64);
                    float pi = __shfl_xor(ai[r], lm, 64);
                    float lo_r = hi ? pr : ar[r], lo_i = hi ? pi : ai[r];
                    float hi_r = hi ? ar[r] : pr, hi_i = hi ? ai[r] : pi;
                    ar[r] = mAr * lo_r - mAi * lo_i + mBr * hi_r - mBi * hi_i;
                    ai[r] = mAr * lo_i + mAi * lo_r + mBr * hi_i + mBi * hi_r;
                }
            }
        }
        if (l == 0) cnot_ring<1>(ar, ai, lane);
        else if (l == 1) cnot_ring<2>(ar, ai, lane);
        else cnot_ring<3>(ar, ai, lane);
    }
    #pragma unroll
    for (int r = 0; r < 32; ++r) {
        Arb[(size_t)k * 2048 + r * 64 + lane] = (_Float16)ar[r];
        Aib[(size_t)k * 2048 + r * 64 + lane] = (_Float16)ai[r];
    }
}

// ================= K1: conv (8192) | circuit (64) | prep_w + zero enc (128) =================
__global__ __launch_bounds__(256) void k1_kernel(const float* __restrict__ x,
                                                 const float* __restrict__ cw,
                                                 const float* __restrict__ cb,
                                                 _Float16* __restrict__ h,
                                                 const float* __restrict__ fw,
                                                 _Float16* __restrict__ wT,
                                                 float* __restrict__ enc,
                                                 const float* __restrict__ dp,
                                                 _Float16* __restrict__ Arb,
                                                 _Float16* __restrict__ Aib) {
    __shared__ __align__(16) float smem[64 * 68];   // 17408 B, overlaid per branch
    int bx = blockIdx.x, t = threadIdx.x;
    if (bx < B_SZ) {
        // ---- conv3x3 SAME + bias + LeakyReLU -> h f16 ----
        float (*xs)[34][37] = (float(*)[34][37])smem;
        int b = bx;
        for (int i = t; i < 2 * 34 * 37; i += 256) ((float*)xs)[i] = 0.f;
        __syncthreads();
        {
            const float4* xp = (const float4*)(x + (size_t)b * 2048);
            float4 v0 = xp[t * 2], v1 = xp[t * 2 + 1];
            float vv[8] = {v0.x, v0.y, v0.z, v0.w, v1.x, v1.y, v1.z, v1.w};
            #pragma unroll
            for (int u = 0; u < 8; ++u) {
                int f = t * 8 + u;
                int ch = f >> 10, ii = (f >> 5) & 31, jj = f & 31;
                xs[ch][ii + 1][jj + 1] = vv[u];
            }
        }
        __syncthreads();
        int o = t >> 7, rem = t & 127, i = rem >> 2, j0 = (rem & 3) * 8;
        float w[2][3][3];
        #pragma unroll
        for (int ic = 0; ic < 2; ++ic)
            #pragma unroll
            for (int di = 0; di < 3; ++di)
                #pragma unroll
                for (int dj = 0; dj < 3; ++dj)
                    w[ic][di][dj] = cw[((o * 2 + ic) * 3 + di) * 3 + dj];
        float b0 = cb[o];
        h8 r;
        #pragma unroll
        for (int u = 0; u < 8; ++u) {
            int j = j0 + u;
            float acc = b0;
            #pragma unroll
            for (int ic = 0; ic < 2; ++ic)
                #pragma unroll
                for (int di = 0; di < 3; ++di)
                    #pragma unroll
                    for (int dj = 0; dj < 3; ++dj)
                        acc += xs[ic][i + di][j + dj] * w[ic][di][dj];
            acc = acc >= 0.f ? acc : 0.3f * acc;
            r[u] = (_Float16)acc;
        }
        *(h8*)(h + (size_t)b * 2048 + o * 1024 + i * 32 + j0) = r;
    } else if (bx < B_SZ + 64) {
        // ---- circuit: 4 sims per block, one per wave ----
        int k = (bx - B_SZ) * 4 + (t >> 6);
        circuit_sim(k, dp, Arb, Aib, t & 63);
    } else {
        // ---- prep: transpose fc_w -> wT f16 (256,2048); zero enc ----
        int pb = bx - (B_SZ + 64);          // [0,128)
        int k0 = (pb & 31) * 64, n0 = (pb >> 5) * 64;
        float (*F)[68] = (float(*)[68])smem;
        {
            int kk = t >> 2, ns = (t & 3) * 16;
            const float4* p = (const float4*)(fw + (size_t)(k0 + kk) * 256 + n0 + ns);
            #pragma unroll
            for (int c = 0; c < 4; ++c) *(float4*)&F[kk][ns + c * 4] = p[c];
        }
        __syncthreads();
        int nn = t >> 2, ks = (t & 3) * 16;
        h8 o0, o1;
        #pragma unroll
        for (int u = 0; u < 16; ++u) {
            _Float16 v = (_Float16)F[ks + u][nn];
            if (u < 8) o0[u] = v; else o1[u - 8] = v;
        }
        size_t base = (size_t)(n0 + nn) * 2048 + k0 + ks;
        *(h8*)(wT + base) = o0;
        *(h8*)(wT + base + 8) = o1;
        float4 z = {0.f, 0.f, 0.f, 0.f};
        float4* e4 = (float4*)enc;
        #pragma unroll
        for (int s = 0; s < 16; ++s) e4[(size_t)pb * 4096 + s * 256 + t] = z;
    }
}

// ================= K2: fc split-K GEMM (x<64) | A transpose (x>=64) =================
__global__ __launch_bounds__(256, 3) void k2_kernel(const _Float16* __restrict__ h,
                                                    const _Float16* __restrict__ wT,
                                                    float* __restrict__ enc,
                                                    const u16* __restrict__ Arb,
                                                    const u16* __restrict__ Aib,
                                                    u16* __restrict__ ArT,
                                                    u16* __restrict__ AiT) {
    __shared__ __align__(16) u16 smem[128 * 32 + 64 * 32];   // 12288 B
    int bx = blockIdx.x, t = threadIdx.x;
    if (bx < 64) {
        // ---- fc: BM=128, BN=64, BK=32, KSPLIT=4; 4 waves, wave tile 64x32 ----
        u16* aS = smem;
        u16* bS = smem + 128 * 32;
        int m0 = bx * 128, n0 = blockIdx.y * 64;
        int kbase = blockIdx.z * 512;
        int wid = t >> 6, l = t & 63;
        int wm = (wid & 1) * 64, wn = (wid >> 1) * 32;
        int lr = l & 15, lg = l >> 4;
        f4 acc[4][2];
        #pragma unroll
        for (int mi = 0; mi < 4; ++mi)
            #pragma unroll
            for (int ni = 0; ni < 2; ++ni) acc[mi][ni] = (f4)(0.f);

        int arow = t >> 2, aslot = t & 3;
        int aswz = (aslot ^ (arow & 3)) << 3;
        const _Float16* ha0 = h + (size_t)(m0 + arow) * 2048 + aslot * 8;
        const _Float16* ha1 = h + (size_t)(m0 + arow + 64) * 2048 + aslot * 8;
        const _Float16* hb  = wT + (size_t)(n0 + arow) * 2048 + aslot * 8;

        u16x8 va0 = *(const u16x8*)(ha0 + kbase);
        u16x8 va1 = *(const u16x8*)(ha1 + kbase);
        u16x8 vb0 = *(const u16x8*)(hb + kbase);

        for (int s = 0; s < 16; ++s) {
            *(u16x8*)&aS[arow * 32 + aswz]        = va0;
            *(u16x8*)&aS[(arow + 64) * 32 + aswz] = va1;
            *(u16x8*)&bS[arow * 32 + aswz]        = vb0;
            int k1 = kbase + (s < 15 ? (s + 1) * 32 : 0);
            u16x8 na0 = *(const u16x8*)(ha0 + k1);
            u16x8 na1 = *(const u16x8*)(ha1 + k1);
            u16x8 nb0 = *(const u16x8*)(hb + k1);
            __syncthreads();
            h8 af[4], bf[2];
            #pragma unroll
            for (int mi = 0; mi < 4; ++mi) {
                int r = wm + mi * 16 + lr;
                af[mi] = *(const h8*)&aS[r * 32 + ((lg ^ (r & 3)) << 3)];
            }
            #pragma unroll
            for (int ni = 0; ni < 2; ++ni) {
                int r = wn + ni * 16 + lr;
                bf[ni] = *(const h8*)&bS[r * 32 + ((lg ^ (r & 3)) << 3)];
            }
            #pragma unroll
            for (int mi = 0; mi < 4; ++mi)
                #pragma unroll
                for (int ni = 0; ni < 2; ++ni)
                    acc[mi][ni] = __builtin_amdgcn_mfma_f32_16x16x32_f16(af[mi], bf[ni], acc[mi][ni], 0, 0, 0);
            __syncthreads();
            va0 = na0; va1 = na1; vb0 = nb0;
        }
        #pragma unroll
        for (int mi = 0; mi < 4; ++mi)
            #pragma unroll
            for (int ni = 0; ni < 2; ++ni)
                #pragma unroll
                for (int e = 0; e < 4; ++e) {
                    int m = m0 + wm + mi * 16 + lg * 4 + e;
                    int n = n0 + wn + ni * 16 + lr;
                    atomicAdd(&enc[(size_t)m * 256 + n], acc[mi][ni][e]);
                }
    } else {
        // ---- transpose f16 (256,2048) -> (2048,256), 256 pieces ----
        int idx = (bx - 64) + 16 * (blockIdx.y + 4 * blockIdx.z);   // [0,256)
        int z = idx >> 7, rem2 = idx & 127;
        int k0 = (rem2 >> 5) * 64, j0 = (rem2 & 31) * 64;
        const u16* src = z ? Aib : Arb;
        u16* dst = z ? AiT : ArT;
        u16 (*T)[72] = (u16(*)[72])smem;
        {
            int kk = t >> 2, js = (t & 3) * 16;
            const u16x8* p = (const u16x8*)(src + (size_t)(k0 + kk) * 2048 + j0 + js);
            *(u16x8*)&T[kk][js] = p[0];
            *(u16x8*)&T[kk][js + 8] = p[1];
        }
        __syncthreads();
        int jj = t >> 2, ks = (t & 3) * 16;
        u16x8 o0, o1;
        #pragma unroll
        for (int u = 0; u < 16; ++u) {
            u16 v = T[ks + u][jj];
            if (u < 8) o0[u] = v; else o1[u - 8] = v;
        }
        size_t base = (size_t)(j0 + jj) * 256 + k0 + ks;
        *(u16x8*)(dst + base) = o0;
        *(u16x8*)(dst + base + 8) = o1;
    }
}

// ================= K3: norm (+bias, nan/clip, triple normalize via single reduction) =================
__device__ __forceinline__ float block_sumsq(float v, float* red) {
    float s = v * v;
    #pragma unroll
    for (int off = 32; off > 0; off >>= 1) s += __shfl_down(s, off, 64);
    int lane = threadIdx.x & 63, wid = threadIdx.x >> 6;
    if (lane == 0) red[wid] = s;
    __syncthreads();
    float t = red[0] + red[1] + red[2] + red[3];
    return t;
}

__global__ __launch_bounds__(256) void norm_kernel(const float* __restrict__ enc,
                                                   const float* __restrict__ fb,
                                                   _Float16* __restrict__ psi) {
    __shared__ float red[4];
    int b = blockIdx.x, tid = threadIdx.x;
    float v = enc[(size_t)b * 256 + tid] + fb[tid];
    if (isnan(v)) v = 0.f;
    else if (isinf(v)) v = (v > 0.f) ? 1.0f : 0.f;
    v = fminf(fmaxf(v, 0.f), 1e7f);
    float t1 = block_sumsq(v, red);
    float s1 = sqrtf(t1) + 1e-10f;
    float t2 = t1 / (s1 * s1);
    float s2 = sqrtf(t2) + 1e-10f;
    float t3 = t2 / (s2 * s2);
    float s3 = sqrtf(t3) + 1e-12f;
    psi[(size_t)b * 256 + tid] = (_Float16)(v / (s1 * s2 * s3));
}

// ================= K4: final out = (psi·Ar)^2 + (psi·Ai)^2 =================
__global__ __launch_bounds__(256, 3) void final_kernel(const _Float16* __restrict__ psi,
                                                       const _Float16* __restrict__ ArT,
                                                       const _Float16* __restrict__ AiT,
                                                       float* __restrict__ out) {
    __shared__ __align__(16) u16 pS[128 * 32];
    __shared__ __align__(16) u16 rS[64 * 32];
    __shared__ __align__(16) u16 iS[64 * 32];
    int t = threadIdx.x;
    int m0 = blockIdx.x * 128, n0 = blockIdx.y * 64;
    int wid = t >> 6, l = t & 63;
    int wm = (wid & 1) * 64, wn = (wid >> 1) * 32;
    int lr = l & 15, lg = l >> 4;
    f4 accR[4][2], accI[4][2];
    #pragma unroll
    for (int mi = 0; mi < 4; ++mi)
        #pragma unroll
        for (int ni = 0; ni < 2; ++ni) { accR[mi][ni] = (f4)(0.f); accI[mi][ni] = (f4)(0.f); }

    int arow = t >> 2, aslot = t & 3;
    int aswz = (aslot ^ (arow & 3)) << 3;
    const _Float16* gp0 = psi + (size_t)(m0 + arow) * 256 + aslot * 8;
    const _Float16* gp1 = psi + (size_t)(m0 + arow + 64) * 256 + aslot * 8;
    const _Float16* gr  = ArT + (size_t)(n0 + arow) * 256 + aslot * 8;
    const _Float16* gi  = AiT + (size_t)(n0 + arow) * 256 + aslot * 8;

    u16x8 vp0 = *(const u16x8*)(gp0);
    u16x8 vp1 = *(const u16x8*)(gp1);
    u16x8 vr  = *(const u16x8*)(gr);
    u16x8 vi  = *(const u16x8*)(gi);

    for (int s = 0; s < 8; ++s) {
        *(u16x8*)&pS[arow * 32 + aswz]        = vp0;
        *(u16x8*)&pS[(arow + 64) * 32 + aswz] = vp1;
        *(u16x8*)&rS[arow * 32 + aswz]        = vr;
        *(u16x8*)&iS[arow * 32 + aswz]        = vi;
        int k1 = (s < 7 ? (s + 1) * 32 : 0);
        u16x8 np0 = *(const u16x8*)(gp0 + k1);
        u16x8 np1 = *(const u16x8*)(gp1 + k1);
        u16x8 nr  = *(const u16x8*)(gr + k1);
        u16x8 ni_ = *(const u16x8*)(gi + k1);
        __syncthreads();
        h8 af[4], rf[2], jf[2];
        #pragma unroll
        for (int mi = 0; mi < 4; ++mi) {
            int r = wm + mi * 16 + lr;
            af[mi] = *(const h8*)&pS[r * 32 + ((lg ^ (r & 3)) << 3)];
        }
        #pragma unroll
        for (int ni2 = 0; ni2 < 2; ++ni2) {
            int r = wn + ni2 * 16 + lr;
            rf[ni2] = *(const h8*)&rS[r * 32 + ((lg ^ (r & 3)) << 3)];
            jf[ni2] = *(const h8*)&iS[r * 32 + ((lg ^ (r & 3)) << 3)];
        }
        #pragma unroll
        for (int mi = 0; mi < 4; ++mi)
            #pragma unroll
            for (int ni2 = 0; ni2 < 2; ++ni2) {
                accR[mi][ni2] = __builtin_amdgcn_mfma_f32_16x16x32_f16(af[mi], rf[ni2], accR[mi][ni2], 0, 0, 0);
                accI[mi][ni2] = __builtin_amdgcn_mfma_f32_16x16x32_f16(af[mi], jf[ni2], accI[mi][ni2], 0, 0, 0);
            }
        __syncthreads();
        vp0 = np0; vp1 = np1; vr = nr; vi = ni_;
    }
    #pragma unroll
    for (int mi = 0; mi < 4; ++mi)
        #pragma unroll
        for (int ni2 = 0; ni2 < 2; ++ni2)
            #pragma unroll
            for (int e = 0; e < 4; ++e) {
                int m = m0 + wm + mi * 16 + lg * 4 + e;
                int n = n0 + wn + ni2 * 16 + lr;
                float re = accR[mi][ni2][e], im = accI[mi][ni2][e];
                out[(size_t)m * 2048 + n] = re * re + im * im;
            }
}

extern "C" void kernel_launch(void* const* d_in, const int* in_sizes, int n_in,
                              void* d_out, int out_size, void* d_ws, size_t ws_size,
                              hipStream_t stream) {
    const float* x  = (const float*)d_in[0];
    const float* cw = (const float*)d_in[1];
    const float* cb = (const float*)d_in[2];
    const float* fw = (const float*)d_in[3];
    const float* fb = (const float*)d_in[4];
    const float* dp = (const float*)d_in[5];
    float* out = (float*)d_out;

    float* enc = (float*)d_ws;                                   // 8 MB
    _Float16* psi = (_Float16*)(enc + (size_t)B_SZ * NK);        // 4 MB
    _Float16* Arb = psi + (size_t)B_SZ * NK;                     // 1 MB
    _Float16* Aib = Arb + (size_t)NK * DIM;                      // 1 MB
    _Float16* ArT = Aib + (size_t)NK * DIM;                      // 1 MB
    _Float16* AiT = ArT + (size_t)NK * DIM;                      // 1 MB
    _Float16* wT  = AiT + (size_t)NK * DIM;                      // 1 MB (17 MB total)

    _Float16* h = (_Float16*)d_out;   // 32 MB in d_out (dead before final overwrites)

    k1_kernel<<<B_SZ + 64 + 128, 256, 0, stream>>>(x, cw, cb, h, fw, wT, enc, dp, Arb, Aib);
    k2_kernel<<<dim3(64 + 16, 4, 4), 256, 0, stream>>>(h, wT, enc,
                                                       (const u16*)Arb, (const u16*)Aib,
                                                       (u16*)ArT, (u16*)AiT);
    norm_kernel<<<B_SZ, 256, 0, stream>>>(enc, fb, psi);
    final_kernel<<<dim3(B_SZ / 128, DIM / 64), 256, 0, stream>>>(psi, ArT, AiT, out);
}

// Round 6
// 284.209 us; speedup vs baseline: 1.0758x; 1.0758x over previous
//
#include <hip/hip_runtime.h>
#include <math.h>

#define B_SZ 8192
#define DIM 2048
#define NK 256

typedef _Float16 h8 __attribute__((ext_vector_type(8)));
typedef _Float16 h4v __attribute__((ext_vector_type(4)));
typedef float f4 __attribute__((ext_vector_type(4)));
typedef unsigned short u16;
typedef u16 u16x8 __attribute__((ext_vector_type(8)));

// ================= circuit sim (register statevector, 1 sim per wave) =================
// flat index j = r*64 + lane ; j bits [5:0]=lane, [10:6]=r. wire w lives at bit 10-w.

template <int R>
__device__ __forceinline__ void cnot_ring(float (&ar)[32], float (&ai)[32], int lane) {
    #pragma unroll
    for (int i = 0; i < 11; ++i) {
        const int c = i, tq = (i + R) % 11;
        const int pc = 10 - c, pt = 10 - tq;
        if (pt >= 6) {                      // target in register bits: in-lane swap
            const int rb = pt - 6;
            #pragma unroll
            for (int r0 = 0; r0 < 32; ++r0) {
                if ((r0 >> rb) & 1) continue;
                const int r1 = r0 | (1 << rb);
                if (pc >= 6) {
                    if ((r0 >> (pc - 6)) & 1) {
                        float t0 = ar[r0]; ar[r0] = ar[r1]; ar[r1] = t0;
                        float t1 = ai[r0]; ai[r0] = ai[r1]; ai[r1] = t1;
                    }
                } else {
                    bool ctl = ((lane >> pc) & 1) != 0;
                    float t0 = ar[r0]; ar[r0] = ctl ? ar[r1] : ar[r0]; ar[r1] = ctl ? t0 : ar[r1];
                    float t1 = ai[r0]; ai[r0] = ctl ? ai[r1] : ai[r0]; ai[r1] = ctl ? t1 : ai[r1];
                }
            }
        } else {                            // target in lane bits: shuffle + select
            const int lm = 1 << pt;
            #pragma unroll
            for (int r = 0; r < 32; ++r) {
                if (pc >= 6) {
                    if ((r >> (pc - 6)) & 1) {
                        ar[r] = __shfl_xor(ar[r], lm, 64);
                        ai[r] = __shfl_xor(ai[r], lm, 64);
                    }
                } else {
                    float pr = __shfl_xor(ar[r], lm, 64);
                    float pi = __shfl_xor(ai[r], lm, 64);
                    bool ctl = ((lane >> pc) & 1) != 0;
                    ar[r] = ctl ? pr : ar[r];
                    ai[r] = ctl ? pi : ai[r];
                }
            }
        }
    }
}

__device__ __forceinline__ void circuit_sim(int k, const float* __restrict__ dp,
                                            float (&ar)[32], float (&ai)[32], int lane) {
    const int tgt = k << 3;
    const int tr = tgt >> 6, tl = tgt & 63;
    #pragma unroll
    for (int r = 0; r < 32; ++r) {
        ar[r] = (r == tr && lane == tl) ? 1.f : 0.f;
        ai[r] = 0.f;
    }
    for (int l = 0; l < 3; ++l) {
        const float* plp = dp + l * 33;
        #pragma unroll
        for (int w = 0; w < 11; ++w) {
            float phi = plp[w * 3 + 0], th = plp[w * 3 + 1], om = plp[w * 3 + 2];
            float cc = cosf(0.5f * th), ss = sinf(0.5f * th);
            float a = 0.5f * (phi + om), bb = 0.5f * (phi - om);
            float ca = cosf(a), sa = sinf(a), cb2 = cosf(bb), sb2 = sinf(bb);
            float m00r =  ca * cc, m00i = -sa * cc;
            float m01r = -cb2 * ss, m01i = -sb2 * ss;
            float m10r =  cb2 * ss, m10i = -sb2 * ss;
            float m11r =  ca * cc, m11i =  sa * cc;
            const int sh = 10 - w;
            if (sh >= 6) {                  // pair within lane, across registers
                const int rb = sh - 6;
                #pragma unroll
                for (int r0 = 0; r0 < 32; ++r0) {
                    if ((r0 >> rb) & 1) continue;
                    const int r1 = r0 | (1 << rb);
                    float a0r = ar[r0], a0i = ai[r0], a1r = ar[r1], a1i = ai[r1];
                    ar[r0] = m00r * a0r - m00i * a0i + m01r * a1r - m01i * a1i;
                    ai[r0] = m00r * a0i + m00i * a0r + m01r * a1i + m01i * a1r;
                    ar[r1] = m10r * a0r - m10i * a0i + m11r * a1r - m11i * a1i;
                    ai[r1] = m10r * a0i + m10i * a0r + m11r * a1i + m11i * a1r;
                }
            } else {                        // pair across lanes: shuffle
                const int lm = 1 << sh;
                const bool hi = (lane & lm) != 0;
                const float mAr = hi ? m10r : m00r, mAi = hi ? m10i : m00i;
                const float mBr = hi ? m11r : m01r, mBi = hi ? m11i : m01i;
                #pragma unroll
                for (int r = 0; r < 32; ++r) {
                    float pr = __shfl_xor(ar[r], lm, 64);
                    float pi = __shfl_xor(ai[r], lm, 64);
                    float lo_r = hi ? pr : ar[r], lo_i = hi ? pi : ai[r];
                    float hi_r = hi ? ar[r] : pr, hi_i = hi ? ai[r] : pi;
                    ar[r] = mAr * lo_r - mAi * lo_i + mBr * hi_r - mBi * hi_i;
                    ai[r] = mAr * lo_i + mAi * lo_r + mBr * hi_i + mBi * hi_r;
                }
            }
        }
        if (l == 0) cnot_ring<1>(ar, ai, lane);
        else if (l == 1) cnot_ring<2>(ar, ai, lane);
        else cnot_ring<3>(ar, ai, lane);
    }
}

// ================= circuit kernel: 4 sims/block + LDS transpose -> ArT/AiT =================
__global__ __launch_bounds__(256) void circuit_kernel(const float* __restrict__ dp,
                                                      _Float16* __restrict__ ArT,
                                                      _Float16* __restrict__ AiT) {
    __shared__ _Float16 lr_[2048][4];
    __shared__ _Float16 li_[2048][4];
    int t = threadIdx.x, wave = t >> 6, lane = t & 63;
    int kb = blockIdx.x * 4, k = kb + wave;
    float ar[32], ai[32];
    circuit_sim(k, dp, ar, ai, lane);
    #pragma unroll
    for (int r = 0; r < 32; ++r) {
        lr_[r * 64 + lane][wave] = (_Float16)ar[r];
        li_[r * 64 + lane][wave] = (_Float16)ai[r];
    }
    __syncthreads();
    #pragma unroll
    for (int s = 0; s < 8; ++s) {
        int j = s * 256 + t;
        *(h4v*)(ArT + (size_t)j * 256 + kb) = *(const h4v*)&lr_[j][0];
        *(h4v*)(AiT + (size_t)j * 256 + kb) = *(const h4v*)&li_[j][0];
    }
}

// ================= K1: conv (8192 blocks) | prep_w + zero enc (128 blocks) =================
__global__ __launch_bounds__(256) void k1_kernel(const float* __restrict__ x,
                                                 const float* __restrict__ cw,
                                                 const float* __restrict__ cb,
                                                 _Float16* __restrict__ h,
                                                 const float* __restrict__ fw,
                                                 _Float16* __restrict__ wT,
                                                 float* __restrict__ enc) {
    __shared__ __align__(16) float smem[64 * 68];   // 17408 B, overlaid per branch
    int bx = blockIdx.x, t = threadIdx.x;
    if (bx < B_SZ) {
        // ---- conv3x3 SAME + bias + LeakyReLU -> h f16 ----
        float (*xs)[34][37] = (float(*)[34][37])smem;
        int b = bx;
        const float4* xp = (const float4*)(x + (size_t)b * 2048);
        float4 v0 = xp[t * 2], v1 = xp[t * 2 + 1];      // issue before zero-fill
        for (int i = t; i < 2 * 34 * 37; i += 256) ((float*)xs)[i] = 0.f;
        __syncthreads();
        {
            float vv[8] = {v0.x, v0.y, v0.z, v0.w, v1.x, v1.y, v1.z, v1.w};
            #pragma unroll
            for (int u = 0; u < 8; ++u) {
                int f = t * 8 + u;
                int ch = f >> 10, ii = (f >> 5) & 31, jj = f & 31;
                xs[ch][ii + 1][jj + 1] = vv[u];
            }
        }
        __syncthreads();
        int o = t >> 7, rem = t & 127, i = rem >> 2, j0 = (rem & 3) * 8;
        float w[2][3][3];
        #pragma unroll
        for (int ic = 0; ic < 2; ++ic)
            #pragma unroll
            for (int di = 0; di < 3; ++di)
                #pragma unroll
                for (int dj = 0; dj < 3; ++dj)
                    w[ic][di][dj] = cw[((o * 2 + ic) * 3 + di) * 3 + dj];
        float b0 = cb[o];
        h8 r;
        #pragma unroll
        for (int u = 0; u < 8; ++u) {
            int j = j0 + u;
            float acc = b0;
            #pragma unroll
            for (int ic = 0; ic < 2; ++ic)
                #pragma unroll
                for (int di = 0; di < 3; ++di)
                    #pragma unroll
                    for (int dj = 0; dj < 3; ++dj)
                        acc += xs[ic][i + di][j + dj] * w[ic][di][dj];
            acc = acc >= 0.f ? acc : 0.3f * acc;
            r[u] = (_Float16)acc;
        }
        *(h8*)(h + (size_t)b * 2048 + o * 1024 + i * 32 + j0) = r;
    } else {
        // ---- prep: transpose fc_w -> wT f16 (256,2048); zero enc ----
        int pb = bx - B_SZ;                 // [0,128)
        int k0 = (pb & 31) * 64, n0 = (pb >> 5) * 64;
        float (*F)[68] = (float(*)[68])smem;
        {
            int kk = t >> 2, ns = (t & 3) * 16;
            const float4* p = (const float4*)(fw + (size_t)(k0 + kk) * 256 + n0 + ns);
            #pragma unroll
            for (int c = 0; c < 4; ++c) *(float4*)&F[kk][ns + c * 4] = p[c];
        }
        __syncthreads();
        int nn = t >> 2, ks = (t & 3) * 16;
        h8 o0, o1;
        #pragma unroll
        for (int u = 0; u < 16; ++u) {
            _Float16 v = (_Float16)F[ks + u][nn];
            if (u < 8) o0[u] = v; else o1[u - 8] = v;
        }
        size_t base = (size_t)(n0 + nn) * 2048 + k0 + ks;
        *(h8*)(wT + base) = o0;
        *(h8*)(wT + base + 8) = o1;
        float4 z = {0.f, 0.f, 0.f, 0.f};
        float4* e4 = (float4*)enc;
        #pragma unroll
        for (int s = 0; s < 16; ++s) e4[(size_t)pb * 4096 + s * 256 + t] = z;
    }
}

// ================= fc: split-K GEMM, swizzled LDS + prefetch =================
// BM=128, BN=64, BK=32, KSPLIT=4 (512 each); 4 waves, wave tile 64x32
__global__ __launch_bounds__(256, 3) void fc_kernel(const _Float16* __restrict__ h,
                                                    const _Float16* __restrict__ wT,
                                                    float* __restrict__ enc) {
    __shared__ __align__(16) u16 aS[128 * 32];
    __shared__ __align__(16) u16 bS[64 * 32];
    int t = threadIdx.x;
    int m0 = blockIdx.x * 128, n0 = blockIdx.y * 64;
    int kbase = blockIdx.z * 512;
    int wid = t >> 6, l = t & 63;
    int wm = (wid & 1) * 64, wn = (wid >> 1) * 32;
    int lr = l & 15, lg = l >> 4;
    f4 acc[4][2];
    #pragma unroll
    for (int mi = 0; mi < 4; ++mi)
        #pragma unroll
        for (int ni = 0; ni < 2; ++ni) acc[mi][ni] = (f4)(0.f);

    int arow = t >> 2, aslot = t & 3;
    int aswz = (aslot ^ (arow & 3)) << 3;
    const _Float16* ha0 = h + (size_t)(m0 + arow) * 2048 + aslot * 8;
    const _Float16* ha1 = h + (size_t)(m0 + arow + 64) * 2048 + aslot * 8;
    const _Float16* hb  = wT + (size_t)(n0 + arow) * 2048 + aslot * 8;

    u16x8 va0 = *(const u16x8*)(ha0 + kbase);
    u16x8 va1 = *(const u16x8*)(ha1 + kbase);
    u16x8 vb0 = *(const u16x8*)(hb + kbase);

    for (int s = 0; s < 16; ++s) {
        *(u16x8*)&aS[arow * 32 + aswz]        = va0;
        *(u16x8*)&aS[(arow + 64) * 32 + aswz] = va1;
        *(u16x8*)&bS[arow * 32 + aswz]        = vb0;
        int k1 = kbase + (s < 15 ? (s + 1) * 32 : 0);
        u16x8 na0 = *(const u16x8*)(ha0 + k1);
        u16x8 na1 = *(const u16x8*)(ha1 + k1);
        u16x8 nb0 = *(const u16x8*)(hb + k1);
        __syncthreads();
        h8 af[4], bf[2];
        #pragma unroll
        for (int mi = 0; mi < 4; ++mi) {
            int r = wm + mi * 16 + lr;
            af[mi] = *(const h8*)&aS[r * 32 + ((lg ^ (r & 3)) << 3)];
        }
        #pragma unroll
        for (int ni = 0; ni < 2; ++ni) {
            int r = wn + ni * 16 + lr;
            bf[ni] = *(const h8*)&bS[r * 32 + ((lg ^ (r & 3)) << 3)];
        }
        #pragma unroll
        for (int mi = 0; mi < 4; ++mi)
            #pragma unroll
            for (int ni = 0; ni < 2; ++ni)
                acc[mi][ni] = __builtin_amdgcn_mfma_f32_16x16x32_f16(af[mi], bf[ni], acc[mi][ni], 0, 0, 0);
        __syncthreads();
        va0 = na0; va1 = na1; vb0 = nb0;
    }
    #pragma unroll
    for (int mi = 0; mi < 4; ++mi)
        #pragma unroll
        for (int ni = 0; ni < 2; ++ni)
            #pragma unroll
            for (int e = 0; e < 4; ++e) {
                int m = m0 + wm + mi * 16 + lg * 4 + e;
                int n = n0 + wn + ni * 16 + lr;
                atomicAdd(&enc[(size_t)m * 256 + n], acc[mi][ni][e]);
            }
}

// ================= norm: +bias, nan/clip, triple normalize (single reduction) =================
__device__ __forceinline__ float block_sumsq(float v, float* red) {
    float s = v * v;
    #pragma unroll
    for (int off = 32; off > 0; off >>= 1) s += __shfl_down(s, off, 64);
    int lane = threadIdx.x & 63, wid = threadIdx.x >> 6;
    if (lane == 0) red[wid] = s;
    __syncthreads();
    float t = red[0] + red[1] + red[2] + red[3];
    return t;
}

__global__ __launch_bounds__(256) void norm_kernel(const float* __restrict__ enc,
                                                   const float* __restrict__ fb,
                                                   _Float16* __restrict__ psi) {
    __shared__ float red[4];
    int b = blockIdx.x, tid = threadIdx.x;
    float v = enc[(size_t)b * 256 + tid] + fb[tid];
    if (isnan(v)) v = 0.f;
    else if (isinf(v)) v = (v > 0.f) ? 1.0f : 0.f;
    v = fminf(fmaxf(v, 0.f), 1e7f);
    float t1 = block_sumsq(v, red);
    float s1 = sqrtf(t1) + 1e-10f;
    float t2 = t1 / (s1 * s1);
    float s2 = sqrtf(t2) + 1e-10f;
    float t3 = t2 / (s2 * s2);
    float s3 = sqrtf(t3) + 1e-12f;
    psi[(size_t)b * 256 + tid] = (_Float16)(v / (s1 * s2 * s3));
}

// ================= final: out = (psi·Ar)^2 + (psi·Ai)^2 =================
// BM=128, BN=64, BK=32, 8 steps; 4 waves, wave tile 64x32 (x2 for R,I)
__global__ __launch_bounds__(256, 3) void final_kernel(const _Float16* __restrict__ psi,
                                                       const _Float16* __restrict__ ArT,
                                                       const _Float16* __restrict__ AiT,
                                                       float* __restrict__ out) {
    __shared__ __align__(16) u16 pS[128 * 32];
    __shared__ __align__(16) u16 rS[64 * 32];
    __shared__ __align__(16) u16 iS[64 * 32];
    int t = threadIdx.x;
    int m0 = blockIdx.x * 128, n0 = blockIdx.y * 64;
    int wid = t >> 6, l = t & 63;
    int wm = (wid & 1) * 64, wn = (wid >> 1) * 32;
    int lr = l & 15, lg = l >> 4;
    f4 accR[4][2], accI[4][2];
    #pragma unroll
    for (int mi = 0; mi < 4; ++mi)
        #pragma unroll
        for (int ni = 0; ni < 2; ++ni) { accR[mi][ni] = (f4)(0.f); accI[mi][ni] = (f4)(0.f); }

    int arow = t >> 2, aslot = t & 3;
    int aswz = (aslot ^ (arow & 3)) << 3;
    const _Float16* gp0 = psi + (size_t)(m0 + arow) * 256 + aslot * 8;
    const _Float16* gp1 = psi + (size_t)(m0 + arow + 64) * 256 + aslot * 8;
    const _Float16* gr  = ArT + (size_t)(n0 + arow) * 256 + aslot * 8;
    const _Float16* gi  = AiT + (size_t)(n0 + arow) * 256 + aslot * 8;

    u16x8 vp0 = *(const u16x8*)(gp0);
    u16x8 vp1 = *(const u16x8*)(gp1);
    u16x8 vr  = *(const u16x8*)(gr);
    u16x8 vi  = *(const u16x8*)(gi);

    for (int s = 0; s < 8; ++s) {
        *(u16x8*)&pS[arow * 32 + aswz]        = vp0;
        *(u16x8*)&pS[(arow + 64) * 32 + aswz] = vp1;
        *(u16x8*)&rS[arow * 32 + aswz]        = vr;
        *(u16x8*)&iS[arow * 32 + aswz]        = vi;
        int k1 = (s < 7 ? (s + 1) * 32 : 0);
        u16x8 np0 = *(const u16x8*)(gp0 + k1);
        u16x8 np1 = *(const u16x8*)(gp1 + k1);
        u16x8 nr  = *(const u16x8*)(gr + k1);
        u16x8 ni_ = *(const u16x8*)(gi + k1);
        __syncthreads();
        h8 af[4], rf[2], jf[2];
        #pragma unroll
        for (int mi = 0; mi < 4; ++mi) {
            int r = wm + mi * 16 + lr;
            af[mi] = *(const h8*)&pS[r * 32 + ((lg ^ (r & 3)) << 3)];
        }
        #pragma unroll
        for (int ni2 = 0; ni2 < 2; ++ni2) {
            int r = wn + ni2 * 16 + lr;
            rf[ni2] = *(const h8*)&rS[r * 32 + ((lg ^ (r & 3)) << 3)];
            jf[ni2] = *(const h8*)&iS[r * 32 + ((lg ^ (r & 3)) << 3)];
        }
        #pragma unroll
        for (int mi = 0; mi < 4; ++mi)
            #pragma unroll
            for (int ni2 = 0; ni2 < 2; ++ni2) {
                accR[mi][ni2] = __builtin_amdgcn_mfma_f32_16x16x32_f16(af[mi], rf[ni2], accR[mi][ni2], 0, 0, 0);
                accI[mi][ni2] = __builtin_amdgcn_mfma_f32_16x16x32_f16(af[mi], jf[ni2], accI[mi][ni2], 0, 0, 0);
            }
        __syncthreads();
        vp0 = np0; vp1 = np1; vr = nr; vi = ni_;
    }
    #pragma unroll
    for (int mi = 0; mi < 4; ++mi)
        #pragma unroll
        for (int ni2 = 0; ni2 < 2; ++ni2)
            #pragma unroll
            for (int e = 0; e < 4; ++e) {
                int m = m0 + wm + mi * 16 + lg * 4 + e;
                int n = n0 + wn + ni2 * 16 + lr;
                float re = accR[mi][ni2][e], im = accI[mi][ni2][e];
                out[(size_t)m * 2048 + n] = re * re + im * im;
            }
}

extern "C" void kernel_launch(void* const* d_in, const int* in_sizes, int n_in,
                              void* d_out, int out_size, void* d_ws, size_t ws_size,
                              hipStream_t stream) {
    const float* x  = (const float*)d_in[0];
    const float* cw = (const float*)d_in[1];
    const float* cb = (const float*)d_in[2];
    const float* fw = (const float*)d_in[3];
    const float* fb = (const float*)d_in[4];
    const float* dp = (const float*)d_in[5];
    float* out = (float*)d_out;

    float* enc = (float*)d_ws;                                   // 8 MB
    _Float16* psi = (_Float16*)(enc + (size_t)B_SZ * NK);        // 4 MB
    _Float16* ArT = psi + (size_t)B_SZ * NK;                     // 1 MB
    _Float16* AiT = ArT + (size_t)DIM * NK;                      // 1 MB
    _Float16* wT  = AiT + (size_t)DIM * NK;                      // 1 MB (15 MB total)

    _Float16* h = (_Float16*)d_out;   // 32 MB in d_out (dead before final overwrites)

    k1_kernel<<<B_SZ + 128, 256, 0, stream>>>(x, cw, cb, h, fw, wT, enc);
    circuit_kernel<<<64, 256, 0, stream>>>(dp, ArT, AiT);
    fc_kernel<<<dim3(B_SZ / 128, 4, 4), 256, 0, stream>>>(h, wT, enc);
    norm_kernel<<<B_SZ, 256, 0, stream>>>(enc, fb, psi);
    final_kernel<<<dim3(B_SZ / 128, DIM / 64), 256, 0, stream>>>(psi, ArT, AiT, out);
}

// Round 7
// 268.140 us; speedup vs baseline: 1.1402x; 1.0599x over previous
//
#include <hip/hip_runtime.h>
#include <math.h>

#define B_SZ 8192
#define DIM 2048
#define NK 256

typedef _Float16 h8 __attribute__((ext_vector_type(8)));
typedef _Float16 h4v __attribute__((ext_vector_type(4)));
typedef float f4 __attribute__((ext_vector_type(4)));
typedef unsigned short u16;
typedef u16 u16x8 __attribute__((ext_vector_type(8)));

// ================= circuit sim (register statevector, 1 sim per wave) =================
// flat index j = r*64 + lane ; j bits [5:0]=lane, [10:6]=r. wire w lives at bit 10-w.

template <int R>
__device__ __forceinline__ void cnot_ring(float (&ar)[32], float (&ai)[32], int lane) {
    #pragma unroll
    for (int i = 0; i < 11; ++i) {
        const int c = i, tq = (i + R) % 11;
        const int pc = 10 - c, pt = 10 - tq;
        if (pt >= 6) {                      // target in register bits: in-lane swap
            const int rb = pt - 6;
            #pragma unroll
            for (int r0 = 0; r0 < 32; ++r0) {
                if ((r0 >> rb) & 1) continue;
                const int r1 = r0 | (1 << rb);
                if (pc >= 6) {
                    if ((r0 >> (pc - 6)) & 1) {
                        float t0 = ar[r0]; ar[r0] = ar[r1]; ar[r1] = t0;
                        float t1 = ai[r0]; ai[r0] = ai[r1]; ai[r1] = t1;
                    }
                } else {
                    bool ctl = ((lane >> pc) & 1) != 0;
                    float t0 = ar[r0]; ar[r0] = ctl ? ar[r1] : ar[r0]; ar[r1] = ctl ? t0 : ar[r1];
                    float t1 = ai[r0]; ai[r0] = ctl ? ai[r1] : ai[r0]; ai[r1] = ctl ? t1 : ai[r1];
                }
            }
        } else {                            // target in lane bits: shuffle + select
            const int lm = 1 << pt;
            #pragma unroll
            for (int r = 0; r < 32; ++r) {
                if (pc >= 6) {
                    if ((r >> (pc - 6)) & 1) {
                        ar[r] = __shfl_xor(ar[r], lm, 64);
                        ai[r] = __shfl_xor(ai[r], lm, 64);
                    }
                } else {
                    float pr = __shfl_xor(ar[r], lm, 64);
                    float pi = __shfl_xor(ai[r], lm, 64);
                    bool ctl = ((lane >> pc) & 1) != 0;
                    ar[r] = ctl ? pr : ar[r];
                    ai[r] = ctl ? pi : ai[r];
                }
            }
        }
    }
}

// gm[g][8] = {m00r,m00i, m01r,m01i, m10r,m10i, m11r,m11i} for gate g = l*11+w
__device__ __forceinline__ void circuit_sim(int k, const float (*__restrict__ gm)[8],
                                            float (&ar)[32], float (&ai)[32], int lane) {
    const int tgt = k << 3;
    const int tr = tgt >> 6, tl = tgt & 63;
    #pragma unroll
    for (int r = 0; r < 32; ++r) {
        ar[r] = (r == tr && lane == tl) ? 1.f : 0.f;
        ai[r] = 0.f;
    }
    for (int l = 0; l < 3; ++l) {
        #pragma unroll
        for (int w = 0; w < 11; ++w) {
            f4 mA = *(const f4*)&gm[l * 11 + w][0];   // m00r,m00i,m01r,m01i
            f4 mB = *(const f4*)&gm[l * 11 + w][4];   // m10r,m10i,m11r,m11i
            float m00r = mA[0], m00i = mA[1], m01r = mA[2], m01i = mA[3];
            float m10r = mB[0], m10i = mB[1], m11r = mB[2], m11i = mB[3];
            const int sh = 10 - w;
            if (sh >= 6) {                  // pair within lane, across registers
                const int rb = sh - 6;
                #pragma unroll
                for (int r0 = 0; r0 < 32; ++r0) {
                    if ((r0 >> rb) & 1) continue;
                    const int r1 = r0 | (1 << rb);
                    float a0r = ar[r0], a0i = ai[r0], a1r = ar[r1], a1i = ai[r1];
                    ar[r0] = m00r * a0r - m00i * a0i + m01r * a1r - m01i * a1i;
                    ai[r0] = m00r * a0i + m00i * a0r + m01r * a1i + m01i * a1r;
                    ar[r1] = m10r * a0r - m10i * a0i + m11r * a1r - m11i * a1i;
                    ai[r1] = m10r * a0i + m10i * a0r + m11r * a1i + m11i * a1r;
                }
            } else {                        // pair across lanes: shuffle
                const int lm = 1 << sh;
                const bool hi = (lane & lm) != 0;
                const float mAr = hi ? m10r : m00r, mAi = hi ? m10i : m00i;
                const float mBr = hi ? m11r : m01r, mBi = hi ? m11i : m01i;
                #pragma unroll
                for (int r = 0; r < 32; ++r) {
                    float pr = __shfl_xor(ar[r], lm, 64);
                    float pi = __shfl_xor(ai[r], lm, 64);
                    float lo_r = hi ? pr : ar[r], lo_i = hi ? pi : ai[r];
                    float hi_r = hi ? ar[r] : pr, hi_i = hi ? ai[r] : pi;
                    ar[r] = mAr * lo_r - mAi * lo_i + mBr * hi_r - mBi * hi_i;
                    ai[r] = mAr * lo_i + mAi * lo_r + mBr * hi_i + mBi * hi_r;
                }
            }
        }
        if (l == 0) cnot_ring<1>(ar, ai, lane);
        else if (l == 1) cnot_ring<2>(ar, ai, lane);
        else cnot_ring<3>(ar, ai, lane);
    }
}

// ================= circuit kernel: parallel gate-matrix precompute + 4 sims/block =================
__global__ __launch_bounds__(256) void circuit_kernel(const float* __restrict__ dp,
                                                      _Float16* __restrict__ ArT,
                                                      _Float16* __restrict__ AiT) {
    __shared__ __align__(16) float gm[33][8];
    __shared__ _Float16 lr_[2048][4];
    __shared__ _Float16 li_[2048][4];
    int t = threadIdx.x, wave = t >> 6, lane = t & 63;
    // ---- all 33 gate matrices computed in parallel (one trig latency total) ----
    if (t < 33) {
        float phi = dp[t * 3 + 0], th = dp[t * 3 + 1], om = dp[t * 3 + 2];
        float cc = cosf(0.5f * th), ss = sinf(0.5f * th);
        float a = 0.5f * (phi + om), bb = 0.5f * (phi - om);
        float ca = cosf(a), sa = sinf(a), cb2 = cosf(bb), sb2 = sinf(bb);
        gm[t][0] =  ca * cc;  gm[t][1] = -sa * cc;    // m00
        gm[t][2] = -cb2 * ss; gm[t][3] = -sb2 * ss;   // m01
        gm[t][4] =  cb2 * ss; gm[t][5] = -sb2 * ss;   // m10
        gm[t][6] =  ca * cc;  gm[t][7] =  sa * cc;    // m11
    }
    __syncthreads();
    int kb = blockIdx.x * 4, k = kb + wave;
    float ar[32], ai[32];
    circuit_sim(k, gm, ar, ai, lane);
    #pragma unroll
    for (int r = 0; r < 32; ++r) {
        lr_[r * 64 + lane][wave] = (_Float16)ar[r];
        li_[r * 64 + lane][wave] = (_Float16)ai[r];
    }
    __syncthreads();
    #pragma unroll
    for (int s = 0; s < 8; ++s) {
        int j = s * 256 + t;
        *(h4v*)(ArT + (size_t)j * 256 + kb) = *(const h4v*)&lr_[j][0];
        *(h4v*)(AiT + (size_t)j * 256 + kb) = *(const h4v*)&li_[j][0];
    }
}

// ================= K1: conv (8192 blocks) | prep_w + zero enc (128 blocks) =================
__global__ __launch_bounds__(256) void k1_kernel(const float* __restrict__ x,
                                                 const float* __restrict__ cw,
                                                 const float* __restrict__ cb,
                                                 _Float16* __restrict__ h,
                                                 const float* __restrict__ fw,
                                                 _Float16* __restrict__ wT,
                                                 float* __restrict__ enc) {
    __shared__ __align__(16) float smem[64 * 68];   // 17408 B, overlaid per branch
    int bx = blockIdx.x, t = threadIdx.x;
    if (bx < B_SZ) {
        // ---- conv3x3 SAME + bias + LeakyReLU -> h f16 ----
        float (*xs)[34][37] = (float(*)[34][37])smem;
        int b = bx;
        const float4* xp = (const float4*)(x + (size_t)b * 2048);
        float4 v0 = xp[t * 2], v1 = xp[t * 2 + 1];      // issue before zero-fill
        for (int i = t; i < 2 * 34 * 37; i += 256) ((float*)xs)[i] = 0.f;
        __syncthreads();
        {
            float vv[8] = {v0.x, v0.y, v0.z, v0.w, v1.x, v1.y, v1.z, v1.w};
            #pragma unroll
            for (int u = 0; u < 8; ++u) {
                int f = t * 8 + u;
                int ch = f >> 10, ii = (f >> 5) & 31, jj = f & 31;
                xs[ch][ii + 1][jj + 1] = vv[u];
            }
        }
        __syncthreads();
        int o = t >> 7, rem = t & 127, i = rem >> 2, j0 = (rem & 3) * 8;
        float w[2][3][3];
        #pragma unroll
        for (int ic = 0; ic < 2; ++ic)
            #pragma unroll
            for (int di = 0; di < 3; ++di)
                #pragma unroll
                for (int dj = 0; dj < 3; ++dj)
                    w[ic][di][dj] = cw[((o * 2 + ic) * 3 + di) * 3 + dj];
        float b0 = cb[o];
        h8 r;
        #pragma unroll
        for (int u = 0; u < 8; ++u) {
            int j = j0 + u;
            float acc = b0;
            #pragma unroll
            for (int ic = 0; ic < 2; ++ic)
                #pragma unroll
                for (int di = 0; di < 3; ++di)
                    #pragma unroll
                    for (int dj = 0; dj < 3; ++dj)
                        acc += xs[ic][i + di][j + dj] * w[ic][di][dj];
            acc = acc >= 0.f ? acc : 0.3f * acc;
            r[u] = (_Float16)acc;
        }
        *(h8*)(h + (size_t)b * 2048 + o * 1024 + i * 32 + j0) = r;
    } else {
        // ---- prep: transpose fc_w -> wT f16 (256,2048); zero enc ----
        int pb = bx - B_SZ;                 // [0,128)
        int k0 = (pb & 31) * 64, n0 = (pb >> 5) * 64;
        float (*F)[68] = (float(*)[68])smem;
        {
            int kk = t >> 2, ns = (t & 3) * 16;
            const float4* p = (const float4*)(fw + (size_t)(k0 + kk) * 256 + n0 + ns);
            #pragma unroll
            for (int c = 0; c < 4; ++c) *(float4*)&F[kk][ns + c * 4] = p[c];
        }
        __syncthreads();
        int nn = t >> 2, ks = (t & 3) * 16;
        h8 o0, o1;
        #pragma unroll
        for (int u = 0; u < 16; ++u) {
            _Float16 v = (_Float16)F[ks + u][nn];
            if (u < 8) o0[u] = v; else o1[u - 8] = v;
        }
        size_t base = (size_t)(n0 + nn) * 2048 + k0 + ks;
        *(h8*)(wT + base) = o0;
        *(h8*)(wT + base + 8) = o1;
        float4 z = {0.f, 0.f, 0.f, 0.f};
        float4* e4 = (float4*)enc;
        #pragma unroll
        for (int s = 0; s < 16; ++s) e4[(size_t)pb * 4096 + s * 256 + t] = z;
    }
}

// ================= fc: split-K GEMM, swizzled LDS + prefetch =================
// BM=128, BN=64, BK=32, KSPLIT=4 (512 each); 4 waves, wave tile 64x32
__global__ __launch_bounds__(256, 3) void fc_kernel(const _Float16* __restrict__ h,
                                                    const _Float16* __restrict__ wT,
                                                    float* __restrict__ enc) {
    __shared__ __align__(16) u16 aS[128 * 32];
    __shared__ __align__(16) u16 bS[64 * 32];
    int t = threadIdx.x;
    int m0 = blockIdx.x * 128, n0 = blockIdx.y * 64;
    int kbase = blockIdx.z * 512;
    int wid = t >> 6, l = t & 63;
    int wm = (wid & 1) * 64, wn = (wid >> 1) * 32;
    int lr = l & 15, lg = l >> 4;
    f4 acc[4][2];
    #pragma unroll
    for (int mi = 0; mi < 4; ++mi)
        #pragma unroll
        for (int ni = 0; ni < 2; ++ni) acc[mi][ni] = (f4)(0.f);

    int arow = t >> 2, aslot = t & 3;
    int aswz = (aslot ^ (arow & 3)) << 3;
    const _Float16* ha0 = h + (size_t)(m0 + arow) * 2048 + aslot * 8;
    const _Float16* ha1 = h + (size_t)(m0 + arow + 64) * 2048 + aslot * 8;
    const _Float16* hb  = wT + (size_t)(n0 + arow) * 2048 + aslot * 8;

    u16x8 va0 = *(const u16x8*)(ha0 + kbase);
    u16x8 va1 = *(const u16x8*)(ha1 + kbase);
    u16x8 vb0 = *(const u16x8*)(hb + kbase);

    for (int s = 0; s < 16; ++s) {
        *(u16x8*)&aS[arow * 32 + aswz]        = va0;
        *(u16x8*)&aS[(arow + 64) * 32 + aswz] = va1;
        *(u16x8*)&bS[arow * 32 + aswz]        = vb0;
        int k1 = kbase + (s < 15 ? (s + 1) * 32 : 0);
        u16x8 na0 = *(const u16x8*)(ha0 + k1);
        u16x8 na1 = *(const u16x8*)(ha1 + k1);
        u16x8 nb0 = *(const u16x8*)(hb + k1);
        __syncthreads();
        h8 af[4], bf[2];
        #pragma unroll
        for (int mi = 0; mi < 4; ++mi) {
            int r = wm + mi * 16 + lr;
            af[mi] = *(const h8*)&aS[r * 32 + ((lg ^ (r & 3)) << 3)];
        }
        #pragma unroll
        for (int ni = 0; ni < 2; ++ni) {
            int r = wn + ni * 16 + lr;
            bf[ni] = *(const h8*)&bS[r * 32 + ((lg ^ (r & 3)) << 3)];
        }
        #pragma unroll
        for (int mi = 0; mi < 4; ++mi)
            #pragma unroll
            for (int ni = 0; ni < 2; ++ni)
                acc[mi][ni] = __builtin_amdgcn_mfma_f32_16x16x32_f16(af[mi], bf[ni], acc[mi][ni], 0, 0, 0);
        __syncthreads();
        va0 = na0; va1 = na1; vb0 = nb0;
    }
    #pragma unroll
    for (int mi = 0; mi < 4; ++mi)
        #pragma unroll
        for (int ni = 0; ni < 2; ++ni)
            #pragma unroll
            for (int e = 0; e < 4; ++e) {
                int m = m0 + wm + mi * 16 + lg * 4 + e;
                int n = n0 + wn + ni * 16 + lr;
                atomicAdd(&enc[(size_t)m * 256 + n], acc[mi][ni][e]);
            }
}

// ================= norm: +bias, nan/clip, triple normalize (single reduction) =================
__device__ __forceinline__ float block_sumsq(float v, float* red) {
    float s = v * v;
    #pragma unroll
    for (int off = 32; off > 0; off >>= 1) s += __shfl_down(s, off, 64);
    int lane = threadIdx.x & 63, wid = threadIdx.x >> 6;
    if (lane == 0) red[wid] = s;
    __syncthreads();
    float t = red[0] + red[1] + red[2] + red[3];
    return t;
}

__global__ __launch_bounds__(256) void norm_kernel(const float* __restrict__ enc,
                                                   const float* __restrict__ fb,
                                                   _Float16* __restrict__ psi) {
    __shared__ float red[4];
    int b = blockIdx.x, tid = threadIdx.x;
    float v = enc[(size_t)b * 256 + tid] + fb[tid];
    if (isnan(v)) v = 0.f;
    else if (isinf(v)) v = (v > 0.f) ? 1.0f : 0.f;
    v = fminf(fmaxf(v, 0.f), 1e7f);
    float t1 = block_sumsq(v, red);
    float s1 = sqrtf(t1) + 1e-10f;
    float t2 = t1 / (s1 * s1);
    float s2 = sqrtf(t2) + 1e-10f;
    float t3 = t2 / (s2 * s2);
    float s3 = sqrtf(t3) + 1e-12f;
    psi[(size_t)b * 256 + tid] = (_Float16)(v / (s1 * s2 * s3));
}

// ================= final: out = (psi·Ar)^2 + (psi·Ai)^2 =================
// BM=128, BN=64, BK=32, 8 steps; 4 waves, wave tile 64x32 (x2 for R,I)
__global__ __launch_bounds__(256, 3) void final_kernel(const _Float16* __restrict__ psi,
                                                       const _Float16* __restrict__ ArT,
                                                       const _Float16* __restrict__ AiT,
                                                       float* __restrict__ out) {
    __shared__ __align__(16) u16 pS[128 * 32];
    __shared__ __align__(16) u16 rS[64 * 32];
    __shared__ __align__(16) u16 iS[64 * 32];
    int t = threadIdx.x;
    int m0 = blockIdx.x * 128, n0 = blockIdx.y * 64;
    int wid = t >> 6, l = t & 63;
    int wm = (wid & 1) * 64, wn = (wid >> 1) * 32;
    int lr = l & 15, lg = l >> 4;
    f4 accR[4][2], accI[4][2];
    #pragma unroll
    for (int mi = 0; mi < 4; ++mi)
        #pragma unroll
        for (int ni = 0; ni < 2; ++ni) { accR[mi][ni] = (f4)(0.f); accI[mi][ni] = (f4)(0.f); }

    int arow = t >> 2, aslot = t & 3;
    int aswz = (aslot ^ (arow & 3)) << 3;
    const _Float16* gp0 = psi + (size_t)(m0 + arow) * 256 + aslot * 8;
    const _Float16* gp1 = psi + (size_t)(m0 + arow + 64) * 256 + aslot * 8;
    const _Float16* gr  = ArT + (size_t)(n0 + arow) * 256 + aslot * 8;
    const _Float16* gi  = AiT + (size_t)(n0 + arow) * 256 + aslot * 8;

    u16x8 vp0 = *(const u16x8*)(gp0);
    u16x8 vp1 = *(const u16x8*)(gp1);
    u16x8 vr  = *(const u16x8*)(gr);
    u16x8 vi  = *(const u16x8*)(gi);

    for (int s = 0; s < 8; ++s) {
        *(u16x8*)&pS[arow * 32 + aswz]        = vp0;
        *(u16x8*)&pS[(arow + 64) * 32 + aswz] = vp1;
        *(u16x8*)&rS[arow * 32 + aswz]        = vr;
        *(u16x8*)&iS[arow * 32 + aswz]        = vi;
        int k1 = (s < 7 ? (s + 1) * 32 : 0);
        u16x8 np0 = *(const u16x8*)(gp0 + k1);
        u16x8 np1 = *(const u16x8*)(gp1 + k1);
        u16x8 nr  = *(const u16x8*)(gr + k1);
        u16x8 ni_ = *(const u16x8*)(gi + k1);
        __syncthreads();
        h8 af[4], rf[2], jf[2];
        #pragma unroll
        for (int mi = 0; mi < 4; ++mi) {
            int r = wm + mi * 16 + lr;
            af[mi] = *(const h8*)&pS[r * 32 + ((lg ^ (r & 3)) << 3)];
        }
        #pragma unroll
        for (int ni2 = 0; ni2 < 2; ++ni2) {
            int r = wn + ni2 * 16 + lr;
            rf[ni2] = *(const h8*)&rS[r * 32 + ((lg ^ (r & 3)) << 3)];
            jf[ni2] = *(const h8*)&iS[r * 32 + ((lg ^ (r & 3)) << 3)];
        }
        #pragma unroll
        for (int mi = 0; mi < 4; ++mi)
            #pragma unroll
            for (int ni2 = 0; ni2 < 2; ++ni2) {
                accR[mi][ni2] = __builtin_amdgcn_mfma_f32_16x16x32_f16(af[mi], rf[ni2], accR[mi][ni2], 0, 0, 0);
                accI[mi][ni2] = __builtin_amdgcn_mfma_f32_16x16x32_f16(af[mi], jf[ni2], accI[mi][ni2], 0, 0, 0);
            }
        __syncthreads();
        vp0 = np0; vp1 = np1; vr = nr; vi = ni_;
    }
    #pragma unroll
    for (int mi = 0; mi < 4; ++mi)
        #pragma unroll
        for (int ni2 = 0; ni2 < 2; ++ni2)
            #pragma unroll
            for (int e = 0; e < 4; ++e) {
                int m = m0 + wm + mi * 16 + lg * 4 + e;
                int n = n0 + wn + ni2 * 16 + lr;
                float re = accR[mi][ni2][e], im = accI[mi][ni2][e];
                out[(size_t)m * 2048 + n] = re * re + im * im;
            }
}

extern "C" void kernel_launch(void* const* d_in, const int* in_sizes, int n_in,
                              void* d_out, int out_size, void* d_ws, size_t ws_size,
                              hipStream_t stream) {
    const float* x  = (const float*)d_in[0];
    const float* cw = (const float*)d_in[1];
    const float* cb = (const float*)d_in[2];
    const float* fw = (const float*)d_in[3];
    const float* fb = (const float*)d_in[4];
    const float* dp = (const float*)d_in[5];
    float* out = (float*)d_out;

    float* enc = (float*)d_ws;                                   // 8 MB
    _Float16* psi = (_Float16*)(enc + (size_t)B_SZ * NK);        // 4 MB
    _Float16* ArT = psi + (size_t)B_SZ * NK;                     // 1 MB
    _Float16* AiT = ArT + (size_t)DIM * NK;                      // 1 MB
    _Float16* wT  = AiT + (size_t)DIM * NK;                      // 1 MB (15 MB total)

    _Float16* h = (_Float16*)d_out;   // 32 MB in d_out (dead before final overwrites)

    k1_kernel<<<B_SZ + 128, 256, 0, stream>>>(x, cw, cb, h, fw, wT, enc);
    circuit_kernel<<<64, 256, 0, stream>>>(dp, ArT, AiT);
    fc_kernel<<<dim3(B_SZ / 128, 4, 4), 256, 0, stream>>>(h, wT, enc);
    norm_kernel<<<B_SZ, 256, 0, stream>>>(enc, fb, psi);
    final_kernel<<<dim3(B_SZ / 128, DIM / 64), 256, 0, stream>>>(psi, ArT, AiT, out);
}